// Round 1
// baseline (519.875 us; speedup 1.0000x reference)
//
#include <hip/hip_runtime.h>
#include <math.h>

#define HW    1024
#define CCH   256
#define NHEAD 8
#define DHEAD 32
#define HIDC  1024
#define BATCH 8

// ---------------------------------------------------------------------------
// BN coefficient precompute: a = g*rsqrt(v+eps), beta = b - m*a
// coef layout: [a1(256) | be1(256) | a2(256) | be2(256)]
// ---------------------------------------------------------------------------
__global__ void bn_coef_kernel(const float* __restrict__ g1, const float* __restrict__ b1,
                               const float* __restrict__ m1, const float* __restrict__ v1,
                               const float* __restrict__ g2, const float* __restrict__ b2,
                               const float* __restrict__ m2, const float* __restrict__ v2,
                               float* __restrict__ coef) {
    int c = threadIdx.x;
    if (c < CCH) {
        float i1 = g1[c] * rsqrtf(v1[c] + 1e-5f);
        coef[c]       = i1;
        coef[256 + c] = b1[c] - m1[c] * i1;
        float i2 = g2[c] * rsqrtf(v2[c] + 1e-5f);
        coef[512 + c] = i2;
        coef[768 + c] = b2[c] - m2[c] * i2;
    }
}

// ---------------------------------------------------------------------------
// Generic fp32 GEMM core: Y[m,n] = sum_k W[m,k] * (X[k,n]*scale[k]+shift[k])
//                                  + bias[m] + resid[m,n]
// Tile 128x128, BK=16, 256 threads, 8x8 per thread. N == HW == 1024.
// ---------------------------------------------------------------------------
__device__ __forceinline__ void gemm_core(const float* __restrict__ W,
                                          const float* __restrict__ X,
                                          const float* __restrict__ scale,
                                          const float* __restrict__ shift,
                                          const float* __restrict__ bias,
                                          const float* __restrict__ resid,
                                          float* __restrict__ Y, int K) {
    __shared__ float As[16][132];   // transposed: As[k][m]
    __shared__ float Bs[16][132];   // Bs[k][n]

    const int tid = threadIdx.x;
    const int tx  = tid & 15;
    const int ty  = tid >> 4;
    const int m0  = blockIdx.y * 128;
    const int n0  = blockIdx.x * 128;

    float acc[8][8];
#pragma unroll
    for (int i = 0; i < 8; ++i)
#pragma unroll
        for (int j = 0; j < 8; ++j) acc[i][j] = 0.f;

    for (int k0 = 0; k0 < K; k0 += 16) {
        // A tile: W[(m0+i)*K + k0+j] -> As[j][i]   (2048 floats)
#pragma unroll
        for (int l = 0; l < 2; ++l) {
            int idx = (tid * 2 + l) * 4;
            int i = idx >> 4;
            int j = idx & 15;
            const float4 a = *(const float4*)(W + (size_t)(m0 + i) * K + k0 + j);
            As[j + 0][i] = a.x; As[j + 1][i] = a.y;
            As[j + 2][i] = a.z; As[j + 3][i] = a.w;
        }
        // B tile: X[(k0+j)*HW + n0+i] (BN fused) -> Bs[j][i]
#pragma unroll
        for (int l = 0; l < 2; ++l) {
            int idx = (tid * 2 + l) * 4;
            int j = idx >> 7;
            int i = idx & 127;
            float4 bv = *(const float4*)(X + (size_t)(k0 + j) * HW + n0 + i);
            if (scale) {
                float sc = scale[k0 + j], sh = shift[k0 + j];
                bv.x = bv.x * sc + sh; bv.y = bv.y * sc + sh;
                bv.z = bv.z * sc + sh; bv.w = bv.w * sc + sh;
            }
            *(float4*)&Bs[j][i] = bv;
        }
        __syncthreads();
#pragma unroll
        for (int kk = 0; kk < 16; ++kk) {
            float4 a0 = *(const float4*)&As[kk][ty * 8];
            float4 a1 = *(const float4*)&As[kk][ty * 8 + 4];
            float4 b0 = *(const float4*)&Bs[kk][tx * 8];
            float4 b1 = *(const float4*)&Bs[kk][tx * 8 + 4];
            const float av[8] = {a0.x, a0.y, a0.z, a0.w, a1.x, a1.y, a1.z, a1.w};
            const float bv[8] = {b0.x, b0.y, b0.z, b0.w, b1.x, b1.y, b1.z, b1.w};
#pragma unroll
            for (int i = 0; i < 8; ++i)
#pragma unroll
                for (int j = 0; j < 8; ++j)
                    acc[i][j] = fmaf(av[i], bv[j], acc[i][j]);
        }
        __syncthreads();
    }
    // epilogue
#pragma unroll
    for (int i = 0; i < 8; ++i) {
        int m = m0 + ty * 8 + i;
        float bi = bias ? bias[m] : 0.f;
#pragma unroll
        for (int j4 = 0; j4 < 2; ++j4) {
            int n = n0 + tx * 8 + j4 * 4;
            float4 r;
            r.x = acc[i][j4 * 4 + 0] + bi;
            r.y = acc[i][j4 * 4 + 1] + bi;
            r.z = acc[i][j4 * 4 + 2] + bi;
            r.w = acc[i][j4 * 4 + 3] + bi;
            if (resid) {
                const float4 rv = *(const float4*)(resid + (size_t)m * HW + n);
                r.x += rv.x; r.y += rv.y; r.z += rv.z; r.w += rv.w;
            }
            *(float4*)(Y + (size_t)m * HW + n) = r;
        }
    }
}

__global__ __launch_bounds__(256)
void gemm_kernel(const float* __restrict__ W, const float* __restrict__ X,
                 const float* __restrict__ scale, const float* __restrict__ shift,
                 const float* __restrict__ bias, const float* __restrict__ resid,
                 float* __restrict__ Y, int K, int M) {
    int b = blockIdx.z;
    gemm_core(W, X + (size_t)b * K * HW, scale, shift, bias,
              resid ? resid + (size_t)b * M * HW : nullptr,
              Y + (size_t)b * M * HW, K);
}

__global__ __launch_bounds__(256)
void qkv_kernel(const float* __restrict__ qw, const float* __restrict__ kw,
                const float* __restrict__ vw, const float* __restrict__ x1,
                const float* __restrict__ x2, const float* __restrict__ a1,
                const float* __restrict__ be1, float* __restrict__ q,
                float* __restrict__ k, float* __restrict__ v) {
    int z = blockIdx.z;
    int b = z / 3;
    int w = z - b * 3;
    const float* W = (w == 0) ? qw : (w == 1 ? kw : vw);
    const float* X = (w == 0) ? x1 : x2;
    float* Y = (w == 0) ? q : (w == 1 ? k : v);
    gemm_core(W, X + (size_t)b * CCH * HW, a1, be1, nullptr, nullptr,
              Y + (size_t)b * CCH * HW, CCH);
}

// ---------------------------------------------------------------------------
// Flash attention, fp32. One block: 128 q-rows of one (b,h).
// Threads: 256 as (tx=0..7, ty=0..31). Thread owns rows ty*4+i (i<4).
// S phase: 4x8 micro-tile over (row, col). PV: 4 rows x 4 dq.
// ---------------------------------------------------------------------------
__global__ __launch_bounds__(256)
void attn_kernel(const float* __restrict__ q, const float* __restrict__ k,
                 const float* __restrict__ v, const float* __restrict__ temp,
                 float* __restrict__ out) {
    __shared__ float q_s[32][132];   // [d][r]
    __shared__ float k_s[32][68];    // [d][j]
    __shared__ float v_s[64][36];    // [j][dq]
    __shared__ float p_s[64][132];   // [j][r] (transposed P)

    const int tid = threadIdx.x;
    const int tx  = tid & 7;
    const int ty  = tid >> 3;
    const int n0  = blockIdx.x * 128;
    const int h   = blockIdx.y;
    const int b   = blockIdx.z;
    const float tmp = temp[h];

    const size_t base = ((size_t)b * CCH + h * DHEAD) * HW;

    // load q tile: 32 x 128
#pragma unroll
    for (int l = 0; l < 4; ++l) {
        int idx = (tid * 4 + l) * 4;
        int d = idx >> 7;
        int r = idx & 127;
        *(float4*)&q_s[d][r] = *(const float4*)(q + base + (size_t)d * HW + n0 + r);
    }

    float m_run[4], l_run[4], acc[4][4];
#pragma unroll
    for (int i = 0; i < 4; ++i) {
        m_run[i] = -1e30f;
        l_run[i] = 0.f;
#pragma unroll
        for (int j = 0; j < 4; ++j) acc[i][j] = 0.f;
    }

    for (int t = 0; t < 16; ++t) {
        const int mm0 = t * 64;
        // load k tile (32x64) and v tile (transposed -> [j][dq])
#pragma unroll
        for (int l = 0; l < 2; ++l) {
            int idx = (tid * 2 + l) * 4;
            int d = idx >> 6;
            int j = idx & 63;
            *(float4*)&k_s[d][j] = *(const float4*)(k + base + (size_t)d * HW + mm0 + j);
            float4 vv = *(const float4*)(v + base + (size_t)d * HW + mm0 + j);
            v_s[j + 0][d] = vv.x; v_s[j + 1][d] = vv.y;
            v_s[j + 2][d] = vv.z; v_s[j + 3][d] = vv.w;
        }
        __syncthreads();

        // S = q^T k  (4 rows x 8 cols)
        float sv[4][8];
#pragma unroll
        for (int i = 0; i < 4; ++i)
#pragma unroll
            for (int j = 0; j < 8; ++j) sv[i][j] = 0.f;

#pragma unroll 8
        for (int d = 0; d < 32; ++d) {
            float4 qv  = *(const float4*)&q_s[d][ty * 4];
            float4 k0v = *(const float4*)&k_s[d][tx * 8];
            float4 k1v = *(const float4*)&k_s[d][tx * 8 + 4];
            const float qa[4] = {qv.x, qv.y, qv.z, qv.w};
            const float ka[8] = {k0v.x, k0v.y, k0v.z, k0v.w, k1v.x, k1v.y, k1v.z, k1v.w};
#pragma unroll
            for (int i = 0; i < 4; ++i)
#pragma unroll
                for (int j = 0; j < 8; ++j)
                    sv[i][j] = fmaf(qa[i], ka[j], sv[i][j]);
        }

        // online softmax update (rows reduced across the 8 tx lanes)
#pragma unroll
        for (int i = 0; i < 4; ++i) {
            float mt = sv[i][0] * tmp;
#pragma unroll
            for (int j = 0; j < 8; ++j) { sv[i][j] *= tmp; mt = fmaxf(mt, sv[i][j]); }
            mt = fmaxf(mt, __shfl_xor(mt, 1));
            mt = fmaxf(mt, __shfl_xor(mt, 2));
            mt = fmaxf(mt, __shfl_xor(mt, 4));
            float mn  = fmaxf(m_run[i], mt);
            float scl = expf(m_run[i] - mn);
            float rs  = 0.f;
#pragma unroll
            for (int j = 0; j < 8; ++j) {
                float p = expf(sv[i][j] - mn);
                sv[i][j] = p;
                rs += p;
            }
            rs += __shfl_xor(rs, 1);
            rs += __shfl_xor(rs, 2);
            rs += __shfl_xor(rs, 4);
            l_run[i] = l_run[i] * scl + rs;
            m_run[i] = mn;
#pragma unroll
            for (int qq = 0; qq < 4; ++qq) acc[i][qq] *= scl;
        }

        // store P transposed
#pragma unroll
        for (int i = 0; i < 4; ++i)
#pragma unroll
            for (int jj = 0; jj < 8; ++jj)
                p_s[tx * 8 + jj][ty * 4 + i] = sv[i][jj];
        __syncthreads();

        // PV: acc[i][qq] += sum_j P[r][j] * V[j][dq]
#pragma unroll 4
        for (int j = 0; j < 64; ++j) {
            float4 pv  = *(const float4*)&p_s[j][ty * 4];
            float4 vvv = *(const float4*)&v_s[j][tx * 4];
            const float pa[4] = {pv.x, pv.y, pv.z, pv.w};
            const float va[4] = {vvv.x, vvv.y, vvv.z, vvv.w};
#pragma unroll
            for (int i = 0; i < 4; ++i)
#pragma unroll
                for (int qq = 0; qq < 4; ++qq)
                    acc[i][qq] = fmaf(pa[i], va[qq], acc[i][qq]);
        }
        __syncthreads();
    }

    // normalize + stage to LDS for coalesced global write
    float (*po)[132] = (float(*)[132])p_s;
#pragma unroll
    for (int i = 0; i < 4; ++i) {
        float inv = 1.0f / l_run[i];
#pragma unroll
        for (int qq = 0; qq < 4; ++qq)
            po[tx * 4 + qq][ty * 4 + i] = acc[i][qq] * inv;
    }
    __syncthreads();
#pragma unroll
    for (int l = 0; l < 4; ++l) {
        int idx = (tid * 4 + l) * 4;
        if (idx < 32 * 128) {
            int dq = idx >> 7;
            int r  = idx & 127;
            *(float4*)(out + base + (size_t)dq * HW + n0 + r) = *(const float4*)&po[dq][r];
        }
    }
}

// ---------------------------------------------------------------------------
// Depthwise 3x3 (SAME, zero pad) + exact GELU
// ---------------------------------------------------------------------------
__global__ __launch_bounds__(256)
void dwgelu_kernel(const float* __restrict__ in, const float* __restrict__ dw,
                   float* __restrict__ out) {
    int idx = blockIdx.x * 256 + threadIdx.x;
    int n  = idx & 1023;
    int bc = idx >> 10;            // b*HID + ch
    int ch = bc & 1023;
    int y = n >> 5, x = n & 31;
    const float* wp = dw + ch * 9;
    const float* ip = in + ((size_t)bc << 10);
    float s = 0.f;
#pragma unroll
    for (int dy = -1; dy <= 1; ++dy) {
        int yy = y + dy;
        if ((unsigned)yy >= 32u) continue;
#pragma unroll
        for (int dx = -1; dx <= 1; ++dx) {
            int xx = x + dx;
            if ((unsigned)xx >= 32u) continue;
            s = fmaf(wp[(dy + 1) * 3 + (dx + 1)], ip[yy * 32 + xx], s);
        }
    }
    out[idx] = 0.5f * s * (1.0f + erff(s * 0.70710678118f));
}

// ---------------------------------------------------------------------------
extern "C" void kernel_launch(void* const* d_in, const int* in_sizes, int n_in,
                              void* d_out, int out_size, void* d_ws, size_t ws_size,
                              hipStream_t stream) {
    const float* x1     = (const float*)d_in[0];
    const float* x2     = (const float*)d_in[1];
    const float* bn1_g  = (const float*)d_in[2];
    const float* bn1_b  = (const float*)d_in[3];
    const float* bn1_m  = (const float*)d_in[4];
    const float* bn1_v  = (const float*)d_in[5];
    const float* q_w    = (const float*)d_in[6];
    const float* k_w    = (const float*)d_in[7];
    const float* v_w    = (const float*)d_in[8];
    const float* temp   = (const float*)d_in[9];
    const float* proj_w = (const float*)d_in[10];
    const float* proj_b = (const float*)d_in[11];
    const float* bn2_g  = (const float*)d_in[12];
    const float* bn2_b  = (const float*)d_in[13];
    const float* bn2_m  = (const float*)d_in[14];
    const float* bn2_v  = (const float*)d_in[15];
    const float* fc1_w  = (const float*)d_in[16];
    const float* fc1_b  = (const float*)d_in[17];
    const float* dw_w   = (const float*)d_in[18];
    const float* fc2_w  = (const float*)d_in[19];
    const float* fc2_b  = (const float*)d_in[20];

    float* ws = (float*)d_ws;
    const size_t SZ = (size_t)BATCH * CCH * HW;   // 2,097,152 floats (8 MB)
    float* qb   = ws;                 // [0,   8MB)
    float* kb   = ws + SZ;            // [8,  16MB)
    float* vb   = ws + 2 * SZ;        // [16, 24MB)
    float* attn = ws + 3 * SZ;        // [24, 32MB)
    float* y1   = ws + 4 * SZ;        // [32, 40MB)
    float* h1   = ws;                 // [0,  32MB) — overlays q/k/v/attn (dead after proj)
    float* h2   = ws + 5 * SZ;        // [40, 72MB)
    float* coef = ws + 9 * SZ;        // 1024 floats

    bn_coef_kernel<<<1, 256, 0, stream>>>(bn1_g, bn1_b, bn1_m, bn1_v,
                                          bn2_g, bn2_b, bn2_m, bn2_v, coef);

    // q,k,v = conv1x1(bn1(x1 or x2))
    qkv_kernel<<<dim3(8, 2, 24), 256, 0, stream>>>(q_w, k_w, v_w, x1, x2,
                                                   coef, coef + 256, qb, kb, vb);

    // attention
    attn_kernel<<<dim3(8, NHEAD, BATCH), 256, 0, stream>>>(qb, kb, vb, temp, attn);

    // y1 = x1 + proj(attn)
    gemm_kernel<<<dim3(8, 2, BATCH), 256, 0, stream>>>(proj_w, attn, nullptr, nullptr,
                                                       proj_b, x1, y1, CCH, CCH);

    // h1 = fc1(bn2(y1))
    gemm_kernel<<<dim3(8, 8, BATCH), 256, 0, stream>>>(fc1_w, y1, coef + 512, coef + 768,
                                                       fc1_b, nullptr, h1, CCH, HIDC);

    // h2 = gelu(dwconv(h1))
    dwgelu_kernel<<<(BATCH * HIDC * HW) / 256, 256, 0, stream>>>(h1, dw_w, h2);

    // out = y1 + fc2(h2)
    gemm_kernel<<<dim3(8, 2, BATCH), 256, 0, stream>>>(fc2_w, h2, nullptr, nullptr,
                                                       fc2_b, y1, (float*)d_out, HIDC, CCH);
}

// Round 2
// 293.624 us; speedup vs baseline: 1.7705x; 1.7705x over previous
//
#include <hip/hip_runtime.h>
#include <math.h>

#define HW    1024
#define CCH   256
#define NHEAD 8
#define HIDC  1024
#define BATCH 8
#define L2E   1.44269504f

typedef unsigned short u16;
typedef __attribute__((ext_vector_type(8))) short  bf16x8;
typedef __attribute__((ext_vector_type(4))) float  f32x4;
typedef __attribute__((ext_vector_type(8))) unsigned short us8;
typedef __attribute__((ext_vector_type(4))) unsigned short us4;

__device__ __forceinline__ u16 f2b(float f) {
    union { float f; unsigned u; } c; c.f = f;
    unsigned r = c.u + 0x7FFFu + ((c.u >> 16) & 1u);
    return (u16)(r >> 16);
}
__device__ __forceinline__ float b2f(u16 u) {
    union { unsigned u; float f; } c; c.u = ((unsigned)u) << 16;
    return c.f;
}

// ---------------------------------------------------------------------------
// BN coefficients: a = g*rsqrt(v+eps), be = b - m*a
// ---------------------------------------------------------------------------
__global__ void bn_coef_kernel(const float* __restrict__ g1, const float* __restrict__ b1,
                               const float* __restrict__ m1, const float* __restrict__ v1,
                               const float* __restrict__ g2, const float* __restrict__ b2,
                               const float* __restrict__ m2, const float* __restrict__ v2,
                               float* __restrict__ coef) {
    int c = threadIdx.x;
    if (c < CCH) {
        float i1 = g1[c] * rsqrtf(v1[c] + 1e-5f);
        coef[c]       = i1;
        coef[256 + c] = b1[c] - m1[c] * i1;
        float i2 = g2[c] * rsqrtf(v2[c] + 1e-5f);
        coef[512 + c] = i2;
        coef[768 + c] = b2[c] - m2[c] * i2;
    }
}

// fp32 -> bf16, 4 elems/thread
__global__ __launch_bounds__(256)
void cvt_w_kernel(const float* __restrict__ src, u16* __restrict__ dst) {
    int i = (blockIdx.x * 256 + threadIdx.x) * 4;
    float4 v = *(const float4*)(src + i);
    us4 o = { f2b(v.x), f2b(v.y), f2b(v.z), f2b(v.w) };
    *(us4*)(dst + i) = o;
}

// x -> bn1(x) -> bf16   (layout [B][C][HW]; channel = (idx>>10)&255)
__global__ __launch_bounds__(256)
void xbn_kernel(const float* __restrict__ x, const float* __restrict__ a,
                const float* __restrict__ be, u16* __restrict__ out) {
    int i = (blockIdx.x * 256 + threadIdx.x) * 4;
    int c = (i >> 10) & 255;
    float sc = a[c], sh = be[c];
    float4 v = *(const float4*)(x + i);
    us4 o = { f2b(v.x * sc + sh), f2b(v.y * sc + sh),
              f2b(v.z * sc + sh), f2b(v.w * sc + sh) };
    *(us4*)(out + i) = o;
}

// ---------------------------------------------------------------------------
// bf16 MFMA GEMM: Y[m,n] = sum_k W[m,k]*X[k,n] (+bias[m]) (+resid) -> outf / outb
// outb optionally gets BN applied (bn_a/bn_be). Tile 128x128, BK=64, 4 waves.
// LDS: 16B-chunk XOR swizzle (chunk ^= row&7) on both operands.
// ---------------------------------------------------------------------------
__global__ __launch_bounds__(256)
void gemm_bf16(const u16* __restrict__ W, const u16* __restrict__ X,
               const float* __restrict__ bias, const float* __restrict__ resid,
               float* __restrict__ outf, u16* __restrict__ outb,
               const float* __restrict__ bn_a, const float* __restrict__ bn_be,
               int K, int M) {
    __shared__ u16 lds_a[128 * 64];
    __shared__ u16 lds_b[128 * 64];

    const int tid = threadIdx.x;
    const int l   = tid & 63;
    const int wid = tid >> 6;
    const int wr  = wid >> 1, wc = wid & 1;
    const int m0  = blockIdx.y * 128, n0 = blockIdx.x * 128;
    const size_t bo = (size_t)blockIdx.z * M * HW;

    X += (size_t)blockIdx.z * K * HW;
    if (resid) resid += bo;
    if (outf)  outf  += bo;
    if (outb)  outb  += bo;

    f32x4 acc[4][4];
#pragma unroll
    for (int i = 0; i < 4; ++i)
#pragma unroll
        for (int j = 0; j < 4; ++j) acc[i][j] = (f32x4)0.f;

    const int kb = tid >> 4;   // 0..15 (4-k group)
    const int nb = tid & 15;   // 0..15 (8-n group)

    for (int k0 = 0; k0 < K; k0 += 64) {
        // --- stage A: W[m0..m0+128)[k0..k0+64) -> lds_a, swizzled 16B chunks
#pragma unroll
        for (int lq = 0; lq < 4; ++lq) {
            int c   = lq * 256 + tid;
            int row = c >> 3, ck = c & 7;
            us8 wv = *(const us8*)(W + (size_t)(m0 + row) * K + k0 + ck * 8);
            *(us8*)(&lds_a[row * 64 + ((ck ^ (row & 7)) * 8)]) = wv;
        }
        // --- stage B: X[k0..][n0..] -> lds_b transposed [n][k], swizzled
        u16 vals[4][8];
#pragma unroll
        for (int e = 0; e < 4; ++e) {
            us8 xv = *(const us8*)(X + (size_t)(k0 + kb * 4 + e) * HW + n0 + nb * 8);
#pragma unroll
            for (int r = 0; r < 8; ++r) vals[e][r] = xv[r];
        }
#pragma unroll
        for (int r = 0; r < 8; ++r) {
            int n = nb * 8 + r;
            us4 pk = { vals[0][r], vals[1][r], vals[2][r], vals[3][r] };
            *(us4*)(&lds_b[n * 64 + ((kb >> 1) ^ (n & 7)) * 8 + (kb & 1) * 4]) = pk;
        }
        __syncthreads();

#pragma unroll
        for (int ks = 0; ks < 2; ++ks) {
            bf16x8 af[4], bfr[4];
#pragma unroll
            for (int mi = 0; mi < 4; ++mi) {
                int row = wr * 64 + mi * 16 + (l & 15);
                int ck  = (ks * 4 + (l >> 4)) ^ (row & 7);
                af[mi] = *(const bf16x8*)(&lds_a[row * 64 + ck * 8]);
            }
#pragma unroll
            for (int ni = 0; ni < 4; ++ni) {
                int n  = wc * 64 + ni * 16 + (l & 15);
                int ck = (ks * 4 + (l >> 4)) ^ (n & 7);
                bfr[ni] = *(const bf16x8*)(&lds_b[n * 64 + ck * 8]);
            }
#pragma unroll
            for (int mi = 0; mi < 4; ++mi)
#pragma unroll
                for (int ni = 0; ni < 4; ++ni)
                    acc[mi][ni] = __builtin_amdgcn_mfma_f32_16x16x32_bf16(
                        af[mi], bfr[ni], acc[mi][ni], 0, 0, 0);
        }
        __syncthreads();
    }

    // epilogue: D lane map col=l&15, row=(l>>4)*4+r
    const int rl = (l >> 4) * 4, cl = l & 15;
#pragma unroll
    for (int mi = 0; mi < 4; ++mi)
#pragma unroll
        for (int ni = 0; ni < 4; ++ni) {
#pragma unroll
            for (int r = 0; r < 4; ++r) {
                int m = m0 + wr * 64 + mi * 16 + rl + r;
                int n = n0 + wc * 64 + ni * 16 + cl;
                float v = acc[mi][ni][r];
                if (bias)  v += bias[m];
                if (resid) v += resid[(size_t)m * HW + n];
                if (outf)  outf[(size_t)m * HW + n] = v;
                if (outb) {
                    float vb = v;
                    if (bn_a) vb = vb * bn_a[m] + bn_be[m];
                    outb[(size_t)m * HW + n] = f2b(vb);
                }
            }
        }
}

// ---------------------------------------------------------------------------
// bf16 MFMA flash attention. Block = 128 q-positions of one (b,h).
// q,k,v bf16 [b][c=h*32+d][n]. 4 waves, each owns 32 q-rows. KBLK=64, d=32.
// ---------------------------------------------------------------------------
__global__ __launch_bounds__(256)
void attn_mfma(const u16* __restrict__ q, const u16* __restrict__ kk,
               const u16* __restrict__ vv, const float* __restrict__ temp,
               u16* __restrict__ out) {
    __shared__ u16 lds_q[128 * 40];  // [n][d], padded
    __shared__ u16 lds_k[64 * 40];   // [j][d]
    __shared__ u16 lds_v[32 * 72];   // [dv][j], padded
    __shared__ u16 lds_p[128 * 72];  // [i][j], padded (wave-local rows)

    const int tid = threadIdx.x, l = tid & 63, wid = tid >> 6;
    const int wbase = wid * 32;
    const int n0 = blockIdx.x * 128;
    const int h = blockIdx.y, b = blockIdx.z;
    const float tmp = temp[h];
    const size_t base = ((size_t)b * CCH + h * 32) * HW;

    {   // stage Q transposed: [n][d]
        int d = tid >> 3, j0 = (tid & 7) * 16;
#pragma unroll
        for (int hf = 0; hf < 2; ++hf) {
            us8 qv = *(const us8*)(q + base + (size_t)d * HW + n0 + j0 + hf * 8);
#pragma unroll
            for (int e = 0; e < 8; ++e) lds_q[(j0 + hf * 8 + e) * 40 + d] = qv[e];
        }
    }

    float m_run[2][4], l_run[2][4];
    f32x4 acc_o[2][2];
#pragma unroll
    for (int mi = 0; mi < 2; ++mi) {
#pragma unroll
        for (int r = 0; r < 4; ++r) { m_run[mi][r] = -1e30f; l_run[mi][r] = 0.f; }
        acc_o[mi][0] = (f32x4)0.f; acc_o[mi][1] = (f32x4)0.f;
    }

    for (int t = 0; t < 16; ++t) {
        const int kv0 = t * 64;
        __syncthreads();   // lds_k/lds_v free (also orders Q staging on t==0)
        {   // stage K transposed [j][d]; V linear [dv][j]
            int d = tid >> 3, j0 = (tid & 7) * 8;
            us8 kv = *(const us8*)(kk + base + (size_t)d * HW + kv0 + j0);
#pragma unroll
            for (int e = 0; e < 8; ++e) lds_k[(j0 + e) * 40 + d] = kv[e];
            us8 vval = *(const us8*)(vv + base + (size_t)d * HW + kv0 + j0);
            *(us8*)(&lds_v[d * 72 + j0]) = vval;
        }
        __syncthreads();

        // S = Q^T K (2 row-tiles x 4 col-tiles), one MFMA k-step (d=32)
        bf16x8 aq[2], bk[4];
#pragma unroll
        for (int mi = 0; mi < 2; ++mi)
            aq[mi] = *(const bf16x8*)(&lds_q[(wbase + mi * 16 + (l & 15)) * 40 + (l >> 4) * 8]);
#pragma unroll
        for (int nj = 0; nj < 4; ++nj)
            bk[nj] = *(const bf16x8*)(&lds_k[(nj * 16 + (l & 15)) * 40 + (l >> 4) * 8]);

        f32x4 s[2][4];
#pragma unroll
        for (int mi = 0; mi < 2; ++mi)
#pragma unroll
            for (int nj = 0; nj < 4; ++nj)
                s[mi][nj] = __builtin_amdgcn_mfma_f32_16x16x32_bf16(
                    aq[mi], bk[nj], (f32x4)0.f, 0, 0, 0);

        // online softmax (row spread over 16 lanes x 4 col-tiles)
#pragma unroll
        for (int mi = 0; mi < 2; ++mi) {
            float mt[4] = {-1e30f, -1e30f, -1e30f, -1e30f};
#pragma unroll
            for (int nj = 0; nj < 4; ++nj)
#pragma unroll
                for (int r = 0; r < 4; ++r) {
                    float sv = s[mi][nj][r] * tmp;
                    s[mi][nj][r] = sv;
                    mt[r] = fmaxf(mt[r], sv);
                }
            float scl[4], mn[4], rs[4];
#pragma unroll
            for (int r = 0; r < 4; ++r) {
                mt[r] = fmaxf(mt[r], __shfl_xor(mt[r], 1));
                mt[r] = fmaxf(mt[r], __shfl_xor(mt[r], 2));
                mt[r] = fmaxf(mt[r], __shfl_xor(mt[r], 4));
                mt[r] = fmaxf(mt[r], __shfl_xor(mt[r], 8));
                mn[r]  = fmaxf(m_run[mi][r], mt[r]);
                scl[r] = exp2f((m_run[mi][r] - mn[r]) * L2E);
                m_run[mi][r] = mn[r];
                rs[r] = 0.f;
            }
#pragma unroll
            for (int nj = 0; nj < 4; ++nj)
#pragma unroll
                for (int r = 0; r < 4; ++r) {
                    float p = exp2f((s[mi][nj][r] - mn[r]) * L2E);
                    s[mi][nj][r] = p;
                    rs[r] += p;
                }
#pragma unroll
            for (int r = 0; r < 4; ++r) {
                rs[r] += __shfl_xor(rs[r], 1);
                rs[r] += __shfl_xor(rs[r], 2);
                rs[r] += __shfl_xor(rs[r], 4);
                rs[r] += __shfl_xor(rs[r], 8);
                l_run[mi][r] = l_run[mi][r] * scl[r] + rs[r];
                acc_o[mi][0][r] *= scl[r];
                acc_o[mi][1][r] *= scl[r];
            }
            // P -> lds_p (bf16), wave-local rows
#pragma unroll
            for (int nj = 0; nj < 4; ++nj)
#pragma unroll
                for (int r = 0; r < 4; ++r)
                    lds_p[(wbase + mi * 16 + (l >> 4) * 4 + r) * 72 + nj * 16 + (l & 15)]
                        = f2b(s[mi][nj][r]);
        }
        asm volatile("s_waitcnt lgkmcnt(0)" ::: "memory");
        __builtin_amdgcn_sched_barrier(0);

        // PV: O += P * V
#pragma unroll
        for (int kj = 0; kj < 2; ++kj) {
            bf16x8 pa[2], vb[2];
#pragma unroll
            for (int mi = 0; mi < 2; ++mi)
                pa[mi] = *(const bf16x8*)(&lds_p[(wbase + mi * 16 + (l & 15)) * 72
                                                 + kj * 32 + (l >> 4) * 8]);
#pragma unroll
            for (int dv = 0; dv < 2; ++dv)
                vb[dv] = *(const bf16x8*)(&lds_v[(dv * 16 + (l & 15)) * 72
                                                 + kj * 32 + (l >> 4) * 8]);
#pragma unroll
            for (int mi = 0; mi < 2; ++mi)
#pragma unroll
                for (int dv = 0; dv < 2; ++dv)
                    acc_o[mi][dv] = __builtin_amdgcn_mfma_f32_16x16x32_bf16(
                        pa[mi], vb[dv], acc_o[mi][dv], 0, 0, 0);
        }
    }

    __syncthreads();   // all PV done before overlaying lds_p with O
    u16* lds_o = lds_p;  // [dv][n] stride 136
#pragma unroll
    for (int mi = 0; mi < 2; ++mi) {
        float inv[4];
#pragma unroll
        for (int r = 0; r < 4; ++r) inv[r] = 1.0f / l_run[mi][r];
#pragma unroll
        for (int dv = 0; dv < 2; ++dv)
#pragma unroll
            for (int r = 0; r < 4; ++r)
                lds_o[(dv * 16 + (l & 15)) * 136 + wbase + mi * 16 + (l >> 4) * 4 + r]
                    = f2b(acc_o[mi][dv][r] * inv[r]);
    }
    __syncthreads();
    {   // coalesced store
        int dv = tid >> 3, i0 = (tid & 7) * 16;
#pragma unroll
        for (int hf = 0; hf < 2; ++hf) {
            us8 ov = *(const us8*)(&lds_o[dv * 136 + i0 + hf * 8]);
            *(us8*)(out + base + (size_t)dv * HW + n0 + i0 + hf * 8) = ov;
        }
    }
}

// ---------------------------------------------------------------------------
// Depthwise 3x3 (SAME) + exact GELU, bf16 in/out, 4 px/thread
// ---------------------------------------------------------------------------
__global__ __launch_bounds__(256)
void dwgelu_bf16(const u16* __restrict__ in, const float* __restrict__ dw,
                 u16* __restrict__ out) {
    int gid = blockIdx.x * 256 + threadIdx.x;
    int x4 = (gid & 7) * 4;
    int y  = (gid >> 3) & 31;
    int bc = gid >> 8;          // uniform within a block
    int ch = bc & 1023;
    const float* wp = dw + ch * 9;
    const u16* ip = in + ((size_t)bc << 10);
    float acc[4] = {0.f, 0.f, 0.f, 0.f};
#pragma unroll
    for (int dy = -1; dy <= 1; ++dy) {
        int yy = y + dy;
        if ((unsigned)yy >= 32u) continue;
        const u16* rp = ip + yy * 32;
        float row[6];
        us4 c4 = *(const us4*)(rp + x4);
        row[1] = b2f(c4[0]); row[2] = b2f(c4[1]);
        row[3] = b2f(c4[2]); row[4] = b2f(c4[3]);
        row[0] = (x4 > 0)  ? b2f(rp[x4 - 1]) : 0.f;
        row[5] = (x4 < 28) ? b2f(rp[x4 + 4]) : 0.f;
        float w0 = wp[(dy + 1) * 3], w1 = wp[(dy + 1) * 3 + 1], w2 = wp[(dy + 1) * 3 + 2];
#pragma unroll
        for (int i = 0; i < 4; ++i)
            acc[i] += w0 * row[i] + w1 * row[i + 1] + w2 * row[i + 2];
    }
    us4 o;
#pragma unroll
    for (int i = 0; i < 4; ++i) {
        float g = 0.5f * acc[i] * (1.0f + erff(acc[i] * 0.70710678118f));
        o[i] = f2b(g);
    }
    *(us4*)(out + (size_t)gid * 4) = o;
}

// ---------------------------------------------------------------------------
extern "C" void kernel_launch(void* const* d_in, const int* in_sizes, int n_in,
                              void* d_out, int out_size, void* d_ws, size_t ws_size,
                              hipStream_t stream) {
    const float* x1     = (const float*)d_in[0];
    const float* x2     = (const float*)d_in[1];
    const float* bn1_g  = (const float*)d_in[2];
    const float* bn1_b  = (const float*)d_in[3];
    const float* bn1_m  = (const float*)d_in[4];
    const float* bn1_v  = (const float*)d_in[5];
    const float* q_w    = (const float*)d_in[6];
    const float* k_w    = (const float*)d_in[7];
    const float* v_w    = (const float*)d_in[8];
    const float* temp   = (const float*)d_in[9];
    const float* proj_w = (const float*)d_in[10];
    const float* proj_b = (const float*)d_in[11];
    const float* bn2_g  = (const float*)d_in[12];
    const float* bn2_b  = (const float*)d_in[13];
    const float* bn2_m  = (const float*)d_in[14];
    const float* bn2_v  = (const float*)d_in[15];
    const float* fc1_w  = (const float*)d_in[16];
    const float* fc1_b  = (const float*)d_in[17];
    const float* dw_w   = (const float*)d_in[18];
    const float* fc2_w  = (const float*)d_in[19];
    const float* fc2_b  = (const float*)d_in[20];

    float* coef = (float*)d_ws;          // 1024 f32
    u16*   bp   = (u16*)(coef + 1024);   // bf16 arena
    const size_t SZ = (size_t)BATCH * CCH * HW;       // 2M elements
    u16* qwb   = bp;                     //  64K
    u16* kwb   = bp + 65536;
    u16* vwb   = bp + 131072;
    u16* pjwb  = bp + 196608;
    u16* fc1wb = bp + 262144;            // 256K
    u16* fc2wb = bp + 524288;            // 256K
    u16* x1n   = bp + 786432;            // 2M
    u16* x2n   = x1n + SZ;
    u16* qb    = x2n + SZ;
    u16* kb    = qb + SZ;
    u16* vb    = kb + SZ;
    u16* attn  = vb + SZ;
    u16* y1n   = attn + SZ;
    u16* h1    = y1n + SZ;               // 8M elements
    u16* h2    = h1 + 4 * SZ;            // 8M elements
    float* y1  = (float*)x1n;            // overlays x1n+x2n (dead after qkv)

    bn_coef_kernel<<<1, 256, 0, stream>>>(bn1_g, bn1_b, bn1_m, bn1_v,
                                          bn2_g, bn2_b, bn2_m, bn2_v, coef);

    cvt_w_kernel<<<64,  256, 0, stream>>>(q_w,    qwb);
    cvt_w_kernel<<<64,  256, 0, stream>>>(k_w,    kwb);
    cvt_w_kernel<<<64,  256, 0, stream>>>(v_w,    vwb);
    cvt_w_kernel<<<64,  256, 0, stream>>>(proj_w, pjwb);
    cvt_w_kernel<<<256, 256, 0, stream>>>(fc1_w,  fc1wb);
    cvt_w_kernel<<<256, 256, 0, stream>>>(fc2_w,  fc2wb);
    xbn_kernel<<<2048, 256, 0, stream>>>(x1, coef, coef + 256, x1n);
    xbn_kernel<<<2048, 256, 0, stream>>>(x2, coef, coef + 256, x2n);

    // q = qw * x1n ; k = kw * x2n ; v = vw * x2n   (bf16 out)
    gemm_bf16<<<dim3(8, 2, 8), 256, 0, stream>>>(qwb, x1n, nullptr, nullptr,
                                                 nullptr, qb, nullptr, nullptr, CCH, CCH);
    gemm_bf16<<<dim3(8, 2, 8), 256, 0, stream>>>(kwb, x2n, nullptr, nullptr,
                                                 nullptr, kb, nullptr, nullptr, CCH, CCH);
    gemm_bf16<<<dim3(8, 2, 8), 256, 0, stream>>>(vwb, x2n, nullptr, nullptr,
                                                 nullptr, vb, nullptr, nullptr, CCH, CCH);

    attn_mfma<<<dim3(8, NHEAD, BATCH), 256, 0, stream>>>(qb, kb, vb, temp, attn);

    // y1 = x1 + proj(attn) (fp32)  and  y1n = bn2(y1) (bf16)
    gemm_bf16<<<dim3(8, 2, 8), 256, 0, stream>>>(pjwb, attn, proj_b, x1,
                                                 y1, y1n, coef + 512, coef + 768, CCH, CCH);

    // h1 = fc1(y1n) + b (bf16)
    gemm_bf16<<<dim3(8, 8, 8), 256, 0, stream>>>(fc1wb, y1n, fc1_b, nullptr,
                                                 nullptr, h1, nullptr, nullptr, CCH, HIDC);

    // h2 = gelu(dw(h1)) (bf16)
    dwgelu_bf16<<<(BATCH * HIDC * HW) / 1024, 256, 0, stream>>>(h1, dw_w, h2);

    // out = y1 + fc2(h2) + b (fp32)
    gemm_bf16<<<dim3(8, 2, 8), 256, 0, stream>>>(fc2wb, h2, fc2_b, y1,
                                                 (float*)d_out, nullptr, nullptr, nullptr,
                                                 HIDC, CCH);
}

// Round 3
// 226.181 us; speedup vs baseline: 2.2985x; 1.2982x over previous
//
#include <hip/hip_runtime.h>
#include <math.h>

#define HW    1024
#define CCH   256
#define NHEAD 8
#define HIDC  1024
#define BATCH 8
#define L2E   1.44269504f

typedef unsigned short u16;
typedef __attribute__((ext_vector_type(8))) short  bf16x8;
typedef __attribute__((ext_vector_type(4))) float  f32x4;
typedef __attribute__((ext_vector_type(8))) unsigned short us8;
typedef __attribute__((ext_vector_type(4))) unsigned short us4;

__device__ __forceinline__ u16 f2b(float f) {
    union { float f; unsigned u; } c; c.f = f;
    unsigned r = c.u + 0x7FFFu + ((c.u >> 16) & 1u);
    return (u16)(r >> 16);
}
__device__ __forceinline__ float b2f(u16 u) {
    union { unsigned u; float f; } c; c.u = ((unsigned)u) << 16;
    return c.f;
}
__device__ __forceinline__ unsigned cvt_pk_bf16(float a, float b) {
    unsigned r;
    asm volatile("v_cvt_pk_bf16_f32 %0, %1, %2" : "=v"(r) : "v"(a), "v"(b));
    return r;  // lo = bf16(a), hi = bf16(b)
}

// ---------------------------------------------------------------------------
// BN coefficients: a = g*rsqrt(v+eps), be = b - m*a
// ---------------------------------------------------------------------------
__global__ void bn_coef_kernel(const float* __restrict__ g1, const float* __restrict__ b1,
                               const float* __restrict__ m1, const float* __restrict__ v1,
                               const float* __restrict__ g2, const float* __restrict__ b2,
                               const float* __restrict__ m2, const float* __restrict__ v2,
                               float* __restrict__ coef) {
    int c = threadIdx.x;
    if (c < CCH) {
        float i1 = g1[c] * rsqrtf(v1[c] + 1e-5f);
        coef[c]       = i1;
        coef[256 + c] = b1[c] - m1[c] * i1;
        float i2 = g2[c] * rsqrtf(v2[c] + 1e-5f);
        coef[512 + c] = i2;
        coef[768 + c] = b2[c] - m2[c] * i2;
    }
}

// all six weight tensors -> bf16, one launch
__global__ __launch_bounds__(256)
void cvt_all(const float* __restrict__ qw, const float* __restrict__ kw,
             const float* __restrict__ vw, const float* __restrict__ pw,
             const float* __restrict__ f1, const float* __restrict__ f2,
             u16* __restrict__ dst) {
    int bid = blockIdx.x;
    const float* src; size_t off; int lb;
    if      (bid < 64)  { src = qw; off = 0;      lb = bid; }
    else if (bid < 128) { src = kw; off = 65536;  lb = bid - 64; }
    else if (bid < 192) { src = vw; off = 131072; lb = bid - 128; }
    else if (bid < 256) { src = pw; off = 196608; lb = bid - 192; }
    else if (bid < 512) { src = f1; off = 262144; lb = bid - 256; }
    else                { src = f2; off = 524288; lb = bid - 512; }
    int i = lb * 1024 + threadIdx.x * 4;
    float4 v = *(const float4*)(src + i);
    us4 o = { f2b(v.x), f2b(v.y), f2b(v.z), f2b(v.w) };
    *(us4*)(dst + off + i) = o;
}

// x1,x2 -> bn1 -> bf16 in one launch
__global__ __launch_bounds__(256)
void xbn2_kernel(const float* __restrict__ x1, const float* __restrict__ x2,
                 const float* __restrict__ a, const float* __restrict__ be,
                 u16* __restrict__ o1, u16* __restrict__ o2) {
    int bid = blockIdx.x;
    const float* x = (bid < 2048) ? x1 : x2;
    u16* o = (bid < 2048) ? o1 : o2;
    int i = ((bid & 2047) * 256 + threadIdx.x) * 4;
    int c = (i >> 10) & 255;
    float sc = a[c], sh = be[c];
    float4 v = *(const float4*)(x + i);
    us4 ov = { f2b(v.x * sc + sh), f2b(v.y * sc + sh),
               f2b(v.z * sc + sh), f2b(v.w * sc + sh) };
    *(us4*)(o + i) = ov;
}

// ---------------------------------------------------------------------------
// Shared bf16 MFMA main loop: acc += W[128,K-tile] * X[K-tile,128]
// ---------------------------------------------------------------------------
__device__ __forceinline__ void mfma_mainloop(const u16* __restrict__ W,
                                              const u16* __restrict__ X,
                                              int K, int m0, int n0,
                                              u16* lds_a, u16* lds_b,
                                              f32x4 acc[4][4]) {
    const int tid = threadIdx.x;
    const int l   = tid & 63;
    const int wr  = (tid >> 6) >> 1, wc = (tid >> 6) & 1;
    const int kb  = tid >> 4, nb = tid & 15;

    for (int k0 = 0; k0 < K; k0 += 64) {
#pragma unroll
        for (int lq = 0; lq < 4; ++lq) {
            int cidx = lq * 256 + tid;
            int row = cidx >> 3, ck = cidx & 7;
            us8 wv = *(const us8*)(W + (size_t)(m0 + row) * K + k0 + ck * 8);
            *(us8*)(&lds_a[row * 64 + ((ck ^ (row & 7)) * 8)]) = wv;
        }
        u16 vals[4][8];
#pragma unroll
        for (int e = 0; e < 4; ++e) {
            us8 xv = *(const us8*)(X + (size_t)(k0 + kb * 4 + e) * HW + n0 + nb * 8);
#pragma unroll
            for (int r = 0; r < 8; ++r) vals[e][r] = xv[r];
        }
#pragma unroll
        for (int r = 0; r < 8; ++r) {
            int n = nb * 8 + r;
            us4 pk = { vals[0][r], vals[1][r], vals[2][r], vals[3][r] };
            *(us4*)(&lds_b[n * 64 + ((kb >> 1) ^ (n & 7)) * 8 + (kb & 1) * 4]) = pk;
        }
        __syncthreads();
#pragma unroll
        for (int ks = 0; ks < 2; ++ks) {
            bf16x8 af[4], bfr[4];
#pragma unroll
            for (int mi = 0; mi < 4; ++mi) {
                int row = wr * 64 + mi * 16 + (l & 15);
                int ck  = (ks * 4 + (l >> 4)) ^ (row & 7);
                af[mi] = *(const bf16x8*)(&lds_a[row * 64 + ck * 8]);
            }
#pragma unroll
            for (int ni = 0; ni < 4; ++ni) {
                int n  = wc * 64 + ni * 16 + (l & 15);
                int ck = (ks * 4 + (l >> 4)) ^ (n & 7);
                bfr[ni] = *(const bf16x8*)(&lds_b[n * 64 + ck * 8]);
            }
#pragma unroll
            for (int mi = 0; mi < 4; ++mi)
#pragma unroll
                for (int ni = 0; ni < 4; ++ni)
                    acc[mi][ni] = __builtin_amdgcn_mfma_f32_16x16x32_bf16(
                        af[mi], bfr[ni], acc[mi][ni], 0, 0, 0);
        }
        __syncthreads();
    }
}

// ---------------------------------------------------------------------------
// Generic GEMM (proj / fc1 / fc2): normal [m][n] outputs
// ---------------------------------------------------------------------------
__global__ __launch_bounds__(256)
void gemm_bf16(const u16* __restrict__ W, const u16* __restrict__ X,
               const float* __restrict__ bias, const float* __restrict__ resid,
               float* __restrict__ outf, u16* __restrict__ outb,
               const float* __restrict__ bn_a, const float* __restrict__ bn_be,
               int K, int M) {
    __shared__ u16 lds_a[128 * 64];
    __shared__ u16 lds_b[128 * 64];
    const int tid = threadIdx.x, l = tid & 63;
    const int wr = (tid >> 6) >> 1, wc = (tid >> 6) & 1;
    const int m0 = blockIdx.y * 128, n0 = blockIdx.x * 128;
    const size_t bo = (size_t)blockIdx.z * M * HW;

    X += (size_t)blockIdx.z * K * HW;
    if (resid) resid += bo;
    if (outf)  outf  += bo;
    if (outb)  outb  += bo;

    f32x4 acc[4][4];
#pragma unroll
    for (int i = 0; i < 4; ++i)
#pragma unroll
        for (int j = 0; j < 4; ++j) acc[i][j] = (f32x4)0.f;

    mfma_mainloop(W, X, K, m0, n0, lds_a, lds_b, acc);

    const int rl = (l >> 4) * 4, cl = l & 15;
#pragma unroll
    for (int mi = 0; mi < 4; ++mi)
#pragma unroll
        for (int ni = 0; ni < 4; ++ni) {
#pragma unroll
            for (int r = 0; r < 4; ++r) {
                int m = m0 + wr * 64 + mi * 16 + rl + r;
                int n = n0 + wc * 64 + ni * 16 + cl;
                float v = acc[mi][ni][r];
                if (bias)  v += bias[m];
                if (resid) v += resid[(size_t)m * HW + n];
                if (outf)  outf[(size_t)m * HW + n] = v;
                if (outb) {
                    float vb = v;
                    if (bn_a) vb = vb * bn_a[m] + bn_be[m];
                    outb[(size_t)m * HW + n] = f2b(vb);
                }
            }
        }
}

// ---------------------------------------------------------------------------
// Fused QKV GEMM. by: 0,1 -> Q (x1n, transposed out), 2,3 -> K (x2n,
// transposed out), 4,5 -> V (x2n, normal out).
// Transposed layout: [b*8+h][n][d] bf16 (d = 32).
// ---------------------------------------------------------------------------
__global__ __launch_bounds__(256)
void qkv_gemm(const u16* __restrict__ wq, const u16* __restrict__ wk,
              const u16* __restrict__ wv, const u16* __restrict__ x1n,
              const u16* __restrict__ x2n, u16* __restrict__ qt,
              u16* __restrict__ kt, u16* __restrict__ vb) {
    __shared__ u16 lds_a[128 * 64];
    __shared__ u16 lds_b[128 * 64];
    const int tid = threadIdx.x, l = tid & 63;
    const int wr = (tid >> 6) >> 1, wc = (tid >> 6) & 1;
    const int by = blockIdx.y, bz = blockIdx.z;
    const int sel = by >> 1;
    const int m0 = (by & 1) * 128, n0 = blockIdx.x * 128;
    const u16* W = (sel == 0) ? wq : (sel == 1) ? wk : wv;
    const u16* X = ((sel == 0) ? x1n : x2n) + (size_t)bz * CCH * HW;

    f32x4 acc[4][4];
#pragma unroll
    for (int i = 0; i < 4; ++i)
#pragma unroll
        for (int j = 0; j < 4; ++j) acc[i][j] = (f32x4)0.f;

    mfma_mainloop(W, X, CCH, m0, n0, lds_a, lds_b, acc);

    const int rl = (l >> 4) * 4, cl = l & 15;
    if (sel < 2) {
        u16* ob = ((sel == 0) ? qt : kt) + (size_t)bz * (NHEAD * HW * 32);
#pragma unroll
        for (int mi = 0; mi < 4; ++mi)
#pragma unroll
            for (int ni = 0; ni < 4; ++ni) {
                int mb = m0 + wr * 64 + mi * 16 + rl;   // 4 consecutive m
                int n  = n0 + wc * 64 + ni * 16 + cl;
                int hh = mb >> 5, d0 = mb & 31;
                us4 ov = { f2b(acc[mi][ni][0]), f2b(acc[mi][ni][1]),
                           f2b(acc[mi][ni][2]), f2b(acc[mi][ni][3]) };
                *(us4*)(ob + ((size_t)hh * HW + n) * 32 + d0) = ov;
            }
    } else {
        u16* ob = vb + (size_t)bz * (CCH * HW);
#pragma unroll
        for (int mi = 0; mi < 4; ++mi)
#pragma unroll
            for (int ni = 0; ni < 4; ++ni) {
                int n = n0 + wc * 64 + ni * 16 + cl;
#pragma unroll
                for (int r = 0; r < 4; ++r) {
                    int m = m0 + wr * 64 + mi * 16 + rl + r;
                    ob[(size_t)m * HW + n] = f2b(acc[mi][ni][r]);
                }
            }
    }
}

// ---------------------------------------------------------------------------
// Flash attention, two-pass, barrier-free. Block = 128 q of one (b,h),
// 4 waves x 32 q-rows. All Q/K/V fragments loaded directly from global.
// Swapped QK^T (S^T = K*Q) makes softmax reductions lane-local.
// Wave-local 4KB LDS for the P bf16 round-trip (XOR-swizzled).
// ---------------------------------------------------------------------------
__global__ __launch_bounds__(256)
void attn_mfma(const u16* __restrict__ qt, const u16* __restrict__ kt,
               const u16* __restrict__ vv, const float* __restrict__ temp,
               u16* __restrict__ out) {
    __shared__ u16 lds[8192];
    const int tid = threadIdx.x, l = tid & 63, w = tid >> 6;
    const int g = l >> 4, c = l & 15;
    const int swz = (c & 7) ^ ((c & 8) >> 1);
    const int n0 = blockIdx.x * 128;
    const int h = blockIdx.y, b = blockIdx.z;
    const int bh = b * NHEAD + h;
    const float t2 = temp[h] * L2E;
    u16* P = lds + w * 2048;

    const u16* qb = qt + ((size_t)bh * HW + n0 + w * 32) * 32;
    const u16* kb = kt + (size_t)bh * HW * 32;
    const u16* vb = vv + ((size_t)b * CCH + h * 32) * HW;

    bf16x8 qf[2];
#pragma unroll
    for (int it = 0; it < 2; ++it)
        qf[it] = *(const bf16x8*)(qb + (it * 16 + c) * 32 + g * 8);

    // pass 1: global max of s*t2 per q-row (lane-local, reduce at end)
    float mx[2] = { -3.0e38f, -3.0e38f };
    for (int t = 0; t < 16; ++t) {
        const u16* kp = kb + (size_t)(t * 64) * 32;
        bf16x8 kf[4];
#pragma unroll
        for (int nj = 0; nj < 4; ++nj)
            kf[nj] = *(const bf16x8*)(kp + (nj * 16 + c) * 32 + g * 8);
#pragma unroll
        for (int it = 0; it < 2; ++it)
#pragma unroll
            for (int nj = 0; nj < 4; ++nj) {
                f32x4 s = __builtin_amdgcn_mfma_f32_16x16x32_bf16(
                    kf[nj], qf[it], (f32x4)0.f, 0, 0, 0);
#pragma unroll
                for (int r = 0; r < 4; ++r) mx[it] = fmaxf(mx[it], s[r] * t2);
            }
    }
#pragma unroll
    for (int it = 0; it < 2; ++it) {
        mx[it] = fmaxf(mx[it], __shfl_xor(mx[it], 16));
        mx[it] = fmaxf(mx[it], __shfl_xor(mx[it], 32));
    }

    // pass 2: P = exp2(s*t2 - mx), accumulate O and l
    float lac[2] = { 0.f, 0.f };
    f32x4 o[2][2];
    o[0][0] = (f32x4)0.f; o[0][1] = (f32x4)0.f;
    o[1][0] = (f32x4)0.f; o[1][1] = (f32x4)0.f;

    for (int t = 0; t < 16; ++t) {
        const int kv0 = t * 64;
        const u16* kp = kb + (size_t)kv0 * 32;
        bf16x8 kf[4];
#pragma unroll
        for (int nj = 0; nj < 4; ++nj)
            kf[nj] = *(const bf16x8*)(kp + (nj * 16 + c) * 32 + g * 8);
        f32x4 s[2][4];
#pragma unroll
        for (int it = 0; it < 2; ++it)
#pragma unroll
            for (int nj = 0; nj < 4; ++nj)
                s[it][nj] = __builtin_amdgcn_mfma_f32_16x16x32_bf16(
                    kf[nj], qf[it], (f32x4)0.f, 0, 0, 0);
        bf16x8 vf[2][2];
#pragma unroll
        for (int kj = 0; kj < 2; ++kj)
#pragma unroll
            for (int dv = 0; dv < 2; ++dv)
                vf[kj][dv] = *(const bf16x8*)(vb + (size_t)(dv * 16 + c) * HW
                                              + kv0 + kj * 32 + g * 8);
#pragma unroll
        for (int it = 0; it < 2; ++it) {
            const int row = it * 16 + c;
#pragma unroll
            for (int nj = 0; nj < 4; ++nj) {
                float p0 = exp2f(fmaf(s[it][nj][0], t2, -mx[it]));
                float p1 = exp2f(fmaf(s[it][nj][1], t2, -mx[it]));
                float p2 = exp2f(fmaf(s[it][nj][2], t2, -mx[it]));
                float p3 = exp2f(fmaf(s[it][nj][3], t2, -mx[it]));
                lac[it] += (p0 + p1) + (p2 + p3);
                uint2 pk;
                pk.x = cvt_pk_bf16(p0, p1);
                pk.y = cvt_pk_bf16(p2, p3);
                int ck = (2 * nj + (g >> 1)) ^ swz;
                *(uint2*)(&P[row * 64 + ck * 8 + (g & 1) * 4]) = pk;
            }
        }
        asm volatile("s_waitcnt lgkmcnt(0)" ::: "memory");
        __builtin_amdgcn_sched_barrier(0);
#pragma unroll
        for (int it = 0; it < 2; ++it) {
            const int row = it * 16 + c;
#pragma unroll
            for (int kj = 0; kj < 2; ++kj) {
                bf16x8 pf = *(const bf16x8*)(&P[row * 64 + ((kj * 4 + g) ^ swz) * 8]);
#pragma unroll
                for (int dv = 0; dv < 2; ++dv)
                    o[it][dv] = __builtin_amdgcn_mfma_f32_16x16x32_bf16(
                        pf, vf[kj][dv], o[it][dv], 0, 0, 0);
            }
        }
    }

#pragma unroll
    for (int it = 0; it < 2; ++it) {
        lac[it] += __shfl_xor(lac[it], 16);
        lac[it] += __shfl_xor(lac[it], 32);
    }
    float inv0 = 1.0f / lac[0], inv1 = 1.0f / lac[1];
    float invr[2][4];
#pragma unroll
    for (int r = 0; r < 4; ++r) {
        int src = (l & 48) | (g * 4 + r);
        invr[0][r] = __shfl(inv0, src);
        invr[1][r] = __shfl(inv1, src);
    }
    asm volatile("s_waitcnt lgkmcnt(0)" ::: "memory");
    __builtin_amdgcn_sched_barrier(0);
    // O -> wave-local LDS [dv][i], stride 36, then coalesced store
#pragma unroll
    for (int it = 0; it < 2; ++it)
#pragma unroll
        for (int dv = 0; dv < 2; ++dv) {
            uint2 pk;
            pk.x = cvt_pk_bf16(o[it][dv][0] * invr[it][0], o[it][dv][1] * invr[it][1]);
            pk.y = cvt_pk_bf16(o[it][dv][2] * invr[it][2], o[it][dv][3] * invr[it][3]);
            *(uint2*)(&P[(dv * 16 + c) * 36 + it * 16 + g * 4]) = pk;
        }
    asm volatile("s_waitcnt lgkmcnt(0)" ::: "memory");
    __builtin_amdgcn_sched_barrier(0);
    {
        int dvl = l & 31, seg = l >> 5;
#pragma unroll
        for (int hf = 0; hf < 2; ++hf) {
            us4 a0 = *(const us4*)(&P[dvl * 36 + seg * 16 + hf * 8]);
            us4 a1 = *(const us4*)(&P[dvl * 36 + seg * 16 + hf * 8 + 4]);
            us8 ov = { a0[0], a0[1], a0[2], a0[3], a1[0], a1[1], a1[2], a1[3] };
            *(us8*)(out + ((size_t)b * CCH + h * 32 + dvl) * HW
                    + n0 + w * 32 + seg * 16 + hf * 8) = ov;
        }
    }
}

// ---------------------------------------------------------------------------
// Depthwise 3x3 (SAME) + exact GELU, bf16 in/out, 4 px/thread
// ---------------------------------------------------------------------------
__global__ __launch_bounds__(256)
void dwgelu_bf16(const u16* __restrict__ in, const float* __restrict__ dw,
                 u16* __restrict__ out) {
    int gid = blockIdx.x * 256 + threadIdx.x;
    int x4 = (gid & 7) * 4;
    int y  = (gid >> 3) & 31;
    int bc = gid >> 8;
    int ch = bc & 1023;
    const float* wp = dw + ch * 9;
    const u16* ip = in + ((size_t)bc << 10);
    float acc[4] = {0.f, 0.f, 0.f, 0.f};
#pragma unroll
    for (int dy = -1; dy <= 1; ++dy) {
        int yy = y + dy;
        if ((unsigned)yy >= 32u) continue;
        const u16* rp = ip + yy * 32;
        float row[6];
        us4 c4 = *(const us4*)(rp + x4);
        row[1] = b2f(c4[0]); row[2] = b2f(c4[1]);
        row[3] = b2f(c4[2]); row[4] = b2f(c4[3]);
        row[0] = (x4 > 0)  ? b2f(rp[x4 - 1]) : 0.f;
        row[5] = (x4 < 28) ? b2f(rp[x4 + 4]) : 0.f;
        float w0 = wp[(dy + 1) * 3], w1 = wp[(dy + 1) * 3 + 1], w2 = wp[(dy + 1) * 3 + 2];
#pragma unroll
        for (int i = 0; i < 4; ++i)
            acc[i] += w0 * row[i] + w1 * row[i + 1] + w2 * row[i + 2];
    }
    us4 o;
#pragma unroll
    for (int i = 0; i < 4; ++i) {
        float ge = 0.5f * acc[i] * (1.0f + erff(acc[i] * 0.70710678118f));
        o[i] = f2b(ge);
    }
    *(us4*)(out + (size_t)gid * 4) = o;
}

// ---------------------------------------------------------------------------
extern "C" void kernel_launch(void* const* d_in, const int* in_sizes, int n_in,
                              void* d_out, int out_size, void* d_ws, size_t ws_size,
                              hipStream_t stream) {
    const float* x1     = (const float*)d_in[0];
    const float* x2     = (const float*)d_in[1];
    const float* bn1_g  = (const float*)d_in[2];
    const float* bn1_b  = (const float*)d_in[3];
    const float* bn1_m  = (const float*)d_in[4];
    const float* bn1_v  = (const float*)d_in[5];
    const float* q_w    = (const float*)d_in[6];
    const float* k_w    = (const float*)d_in[7];
    const float* v_w    = (const float*)d_in[8];
    const float* temp   = (const float*)d_in[9];
    const float* proj_w = (const float*)d_in[10];
    const float* proj_b = (const float*)d_in[11];
    const float* bn2_g  = (const float*)d_in[12];
    const float* bn2_b  = (const float*)d_in[13];
    const float* bn2_m  = (const float*)d_in[14];
    const float* bn2_v  = (const float*)d_in[15];
    const float* fc1_w  = (const float*)d_in[16];
    const float* fc1_b  = (const float*)d_in[17];
    const float* dw_w   = (const float*)d_in[18];
    const float* fc2_w  = (const float*)d_in[19];
    const float* fc2_b  = (const float*)d_in[20];

    const size_t SZ = (size_t)BATCH * CCH * HW;   // 2,097,152 elems
    float* coef = (float*)d_ws;                    // 1024 f32
    u16*   bp   = (u16*)(coef + 1024);
    u16* qwb   = bp;
    u16* kwb   = bp + 65536;
    u16* vwb   = bp + 131072;
    u16* pjwb  = bp + 196608;
    u16* fc1wb = bp + 262144;
    u16* fc2wb = bp + 524288;
    u16* qtb   = bp + 786432;        // [bh][n][d] transposed
    u16* ktb   = qtb + SZ;
    u16* vbuf  = ktb + SZ;           // [b][c][n]
    u16* attnb = vbuf + SZ;
    u16* x1n   = attnb + SZ;
    u16* x2n   = x1n + SZ;
    u16* ext   = x2n + SZ;           // 2*SZ fresh (tail of h2)
    float* y1  = (float*)(ext + 2 * SZ);
    u16* y1n   = (u16*)(y1 + SZ);
    u16* h1    = qtb;                // overlays qt,kt,v,attn (dead by fc1)
    u16* h2    = x1n;                // overlays x1n,x2n + ext (dead by dwgelu)

    bn_coef_kernel<<<1, 256, 0, stream>>>(bn1_g, bn1_b, bn1_m, bn1_v,
                                          bn2_g, bn2_b, bn2_m, bn2_v, coef);
    cvt_all<<<768, 256, 0, stream>>>(q_w, k_w, v_w, proj_w, fc1_w, fc2_w, bp);
    xbn2_kernel<<<4096, 256, 0, stream>>>(x1, x2, coef, coef + 256, x1n, x2n);

    qkv_gemm<<<dim3(8, 6, BATCH), 256, 0, stream>>>(qwb, kwb, vwb, x1n, x2n,
                                                    qtb, ktb, vbuf);

    attn_mfma<<<dim3(8, NHEAD, BATCH), 256, 0, stream>>>(qtb, ktb, vbuf, temp, attnb);

    // y1 = x1 + proj(attn) (fp32); y1n = bn2(y1) (bf16)
    gemm_bf16<<<dim3(8, 2, BATCH), 256, 0, stream>>>(pjwb, attnb, proj_b, x1,
                                                     y1, y1n, coef + 512, coef + 768,
                                                     CCH, CCH);
    // h1 = fc1(y1n) + b (bf16)
    gemm_bf16<<<dim3(8, 8, BATCH), 256, 0, stream>>>(fc1wb, y1n, fc1_b, nullptr,
                                                     nullptr, h1, nullptr, nullptr,
                                                     CCH, HIDC);
    // h2 = gelu(dw(h1))
    dwgelu_bf16<<<(BATCH * HIDC * HW) / 1024, 256, 0, stream>>>(h1, dw_w, h2);

    // out = y1 + fc2(h2) + b (fp32)
    gemm_bf16<<<dim3(8, 2, BATCH), 256, 0, stream>>>(fc2wb, h2, fc2_b, y1,
                                                     (float*)d_out, nullptr,
                                                     nullptr, nullptr, HIDC, CCH);
}

// Round 4
// 147.456 us; speedup vs baseline: 3.5256x; 1.5339x over previous
//
#include <hip/hip_runtime.h>
#include <math.h>

#define HW    1024
#define CCH   256
#define NHEAD 8
#define HIDC  1024
#define BATCH 8
#define L2E   1.44269504f

typedef unsigned short u16;
typedef __attribute__((ext_vector_type(8))) short  bf16x8;
typedef __attribute__((ext_vector_type(4))) float  f32x4;
typedef __attribute__((ext_vector_type(8))) unsigned short us8;
typedef __attribute__((ext_vector_type(4))) unsigned short us4;

__device__ __forceinline__ u16 f2b(float f) {
    union { float f; unsigned u; } c; c.f = f;
    unsigned r = c.u + 0x7FFFu + ((c.u >> 16) & 1u);
    return (u16)(r >> 16);
}
__device__ __forceinline__ float b2f(u16 u) {
    union { unsigned u; float f; } c; c.u = ((unsigned)u) << 16;
    return c.f;
}
__device__ __forceinline__ unsigned cvt_pk_bf16(float a, float b) {
    unsigned r;
    asm volatile("v_cvt_pk_bf16_f32 %0, %1, %2" : "=v"(r) : "v"(a), "v"(b));
    return r;
}

// ---------------------------------------------------------------------------
__global__ void bn_coef_kernel(const float* __restrict__ g1, const float* __restrict__ b1,
                               const float* __restrict__ m1, const float* __restrict__ v1,
                               const float* __restrict__ g2, const float* __restrict__ b2,
                               const float* __restrict__ m2, const float* __restrict__ v2,
                               float* __restrict__ coef) {
    int c = threadIdx.x;
    if (c < CCH) {
        float i1 = g1[c] * rsqrtf(v1[c] + 1e-5f);
        coef[c]       = i1;
        coef[256 + c] = b1[c] - m1[c] * i1;
        float i2 = g2[c] * rsqrtf(v2[c] + 1e-5f);
        coef[512 + c] = i2;
        coef[768 + c] = b2[c] - m2[c] * i2;
    }
}

__global__ __launch_bounds__(256)
void cvt_all(const float* __restrict__ qw, const float* __restrict__ kw,
             const float* __restrict__ vw, const float* __restrict__ pw,
             const float* __restrict__ f1, const float* __restrict__ f2,
             u16* __restrict__ dst) {
    int bid = blockIdx.x;
    const float* src; size_t off; int lb;
    if      (bid < 64)  { src = qw; off = 0;      lb = bid; }
    else if (bid < 128) { src = kw; off = 65536;  lb = bid - 64; }
    else if (bid < 192) { src = vw; off = 131072; lb = bid - 128; }
    else if (bid < 256) { src = pw; off = 196608; lb = bid - 192; }
    else if (bid < 512) { src = f1; off = 262144; lb = bid - 256; }
    else                { src = f2; off = 524288; lb = bid - 512; }
    int i = lb * 1024 + threadIdx.x * 4;
    float4 v = *(const float4*)(src + i);
    us4 o = { f2b(v.x), f2b(v.y), f2b(v.z), f2b(v.w) };
    *(us4*)(dst + off + i) = o;
}

__global__ __launch_bounds__(256)
void xbn2_kernel(const float* __restrict__ x1, const float* __restrict__ x2,
                 const float* __restrict__ a, const float* __restrict__ be,
                 u16* __restrict__ o1, u16* __restrict__ o2) {
    int bid = blockIdx.x;
    const float* x = (bid < 2048) ? x1 : x2;
    u16* o = (bid < 2048) ? o1 : o2;
    int i = ((bid & 2047) * 256 + threadIdx.x) * 4;
    int c = (i >> 10) & 255;
    float sc = a[c], sh = be[c];
    float4 v = *(const float4*)(x + i);
    us4 ov = { f2b(v.x * sc + sh), f2b(v.y * sc + sh),
               f2b(v.z * sc + sh), f2b(v.w * sc + sh) };
    *(us4*)(o + i) = ov;
}

// ---------------------------------------------------------------------------
// 64x64 MFMA main loop (BK=64, 4 waves, wave = 32x32 = 2x2 fragments).
// XOR-swizzled LDS, same involution as the proven 128-tile scheme.
// ---------------------------------------------------------------------------
__device__ __forceinline__ void mfma_loop64(const u16* __restrict__ W,
                                            const u16* __restrict__ X,
                                            int K, int m0, int n0,
                                            u16* lds_a, u16* lds_b,
                                            f32x4 acc[2][2]) {
    const int tid = threadIdx.x;
    const int l   = tid & 63;
    const int wr  = (tid >> 6) >> 1, wc = (tid >> 6) & 1;
    const int kg  = tid >> 4;      // 0..15 -> k = kg*4+e
    const int nb  = tid & 15;      // 0..15 -> n = nb*4+r

    for (int k0 = 0; k0 < K; k0 += 64) {
        // A stage: 64 rows x 64 k, 2 us8 per thread, swizzled chunks
#pragma unroll
        for (int lq = 0; lq < 2; ++lq) {
            int c   = tid * 2 + lq;
            int row = c >> 3, ck = c & 7;
            us8 wv = *(const us8*)(W + (size_t)(m0 + row) * K + k0 + ck * 8);
            *(us8*)(&lds_a[row * 64 + ((ck ^ (row & 7)) * 8)]) = wv;
        }
        // B stage: X[k][n] -> lds_b[n][k] transposed, swizzled
        u16 vals[4][4];
#pragma unroll
        for (int e = 0; e < 4; ++e) {
            us4 xv = *(const us4*)(X + (size_t)(k0 + kg * 4 + e) * HW + n0 + nb * 4);
#pragma unroll
            for (int r = 0; r < 4; ++r) vals[e][r] = xv[r];
        }
#pragma unroll
        for (int r = 0; r < 4; ++r) {
            int n = nb * 4 + r;
            us4 pk = { vals[0][r], vals[1][r], vals[2][r], vals[3][r] };
            *(us4*)(&lds_b[n * 64 + ((kg >> 1) ^ (n & 7)) * 8 + (kg & 1) * 4]) = pk;
        }
        __syncthreads();
#pragma unroll
        for (int ks = 0; ks < 2; ++ks) {
            bf16x8 af[2], bfr[2];
#pragma unroll
            for (int mi = 0; mi < 2; ++mi) {
                int row = wr * 32 + mi * 16 + (l & 15);
                int ck  = (ks * 4 + (l >> 4)) ^ (row & 7);
                af[mi] = *(const bf16x8*)(&lds_a[row * 64 + ck * 8]);
            }
#pragma unroll
            for (int ni = 0; ni < 2; ++ni) {
                int n  = wc * 32 + ni * 16 + (l & 15);
                int ck = (ks * 4 + (l >> 4)) ^ (n & 7);
                bfr[ni] = *(const bf16x8*)(&lds_b[n * 64 + ck * 8]);
            }
#pragma unroll
            for (int mi = 0; mi < 2; ++mi)
#pragma unroll
                for (int ni = 0; ni < 2; ++ni)
                    acc[mi][ni] = __builtin_amdgcn_mfma_f32_16x16x32_bf16(
                        af[mi], bfr[ni], acc[mi][ni], 0, 0, 0);
        }
        __syncthreads();
    }
}

// ---------------------------------------------------------------------------
// Generic GEMM (proj / fc1 / fc2), 64x64 tiles
// ---------------------------------------------------------------------------
__global__ __launch_bounds__(256, 4)
void gemm_bf16(const u16* __restrict__ W, const u16* __restrict__ X,
               const float* __restrict__ bias, const float* __restrict__ resid,
               float* __restrict__ outf, u16* __restrict__ outb,
               const float* __restrict__ bn_a, const float* __restrict__ bn_be,
               int K, int M) {
    __shared__ u16 lds_a[64 * 64];
    __shared__ u16 lds_b[64 * 64];
    const int tid = threadIdx.x, l = tid & 63;
    const int wr = (tid >> 6) >> 1, wc = (tid >> 6) & 1;
    const int m0 = blockIdx.y * 64, n0 = blockIdx.x * 64;
    const size_t bo = (size_t)blockIdx.z * M * HW;

    X += (size_t)blockIdx.z * K * HW;
    if (resid) resid += bo;
    if (outf)  outf  += bo;
    if (outb)  outb  += bo;

    f32x4 acc[2][2];
    acc[0][0] = (f32x4)0.f; acc[0][1] = (f32x4)0.f;
    acc[1][0] = (f32x4)0.f; acc[1][1] = (f32x4)0.f;

    mfma_loop64(W, X, K, m0, n0, lds_a, lds_b, acc);

    const int rl = (l >> 4) * 4, cl = l & 15;
#pragma unroll
    for (int mi = 0; mi < 2; ++mi)
#pragma unroll
        for (int ni = 0; ni < 2; ++ni) {
#pragma unroll
            for (int r = 0; r < 4; ++r) {
                int m = m0 + wr * 32 + mi * 16 + rl + r;
                int n = n0 + wc * 32 + ni * 16 + cl;
                float v = acc[mi][ni][r];
                if (bias)  v += bias[m];
                if (resid) v += resid[(size_t)m * HW + n];
                if (outf)  outf[(size_t)m * HW + n] = v;
                if (outb) {
                    float vb = v;
                    if (bn_a) vb = vb * bn_a[m] + bn_be[m];
                    outb[(size_t)m * HW + n] = f2b(vb);
                }
            }
        }
}

// ---------------------------------------------------------------------------
// Fused QKV GEMM, 64x64 tiles. blockIdx.y 0..11: sel = y>>2 (0=Q,1=K,2=V),
// m0 = (y&3)*64. Q,K write transposed [b*8+h][n][d]; V writes [b][c][n].
// ---------------------------------------------------------------------------
__global__ __launch_bounds__(256, 4)
void qkv_gemm(const u16* __restrict__ wq, const u16* __restrict__ wk,
              const u16* __restrict__ wv, const u16* __restrict__ x1n,
              const u16* __restrict__ x2n, u16* __restrict__ qt,
              u16* __restrict__ kt, u16* __restrict__ vb) {
    __shared__ u16 lds_a[64 * 64];
    __shared__ u16 lds_b[64 * 64];
    const int tid = threadIdx.x, l = tid & 63;
    const int wr = (tid >> 6) >> 1, wc = (tid >> 6) & 1;
    const int by = blockIdx.y, bz = blockIdx.z;
    const int sel = by >> 2;
    const int m0 = (by & 3) * 64, n0 = blockIdx.x * 64;
    const u16* W = (sel == 0) ? wq : (sel == 1) ? wk : wv;
    const u16* X = ((sel == 0) ? x1n : x2n) + (size_t)bz * CCH * HW;

    f32x4 acc[2][2];
    acc[0][0] = (f32x4)0.f; acc[0][1] = (f32x4)0.f;
    acc[1][0] = (f32x4)0.f; acc[1][1] = (f32x4)0.f;

    mfma_loop64(W, X, CCH, m0, n0, lds_a, lds_b, acc);

    const int rl = (l >> 4) * 4, cl = l & 15;
    if (sel < 2) {
        u16* ob = ((sel == 0) ? qt : kt) + (size_t)bz * (NHEAD * HW * 32);
#pragma unroll
        for (int mi = 0; mi < 2; ++mi)
#pragma unroll
            for (int ni = 0; ni < 2; ++ni) {
                int mb = m0 + wr * 32 + mi * 16 + rl;   // 4 consecutive channels
                int n  = n0 + wc * 32 + ni * 16 + cl;
                int hh = mb >> 5, d0 = mb & 31;
                us4 ov = { f2b(acc[mi][ni][0]), f2b(acc[mi][ni][1]),
                           f2b(acc[mi][ni][2]), f2b(acc[mi][ni][3]) };
                *(us4*)(ob + ((size_t)hh * HW + n) * 32 + d0) = ov;
            }
    } else {
        u16* ob = vb + (size_t)bz * (CCH * HW);
#pragma unroll
        for (int mi = 0; mi < 2; ++mi)
#pragma unroll
            for (int ni = 0; ni < 2; ++ni) {
                int n = n0 + wc * 32 + ni * 16 + cl;
#pragma unroll
                for (int r = 0; r < 4; ++r) {
                    int m = m0 + wr * 32 + mi * 16 + rl + r;
                    ob[(size_t)m * HW + n] = f2b(acc[mi][ni][r]);
                }
            }
    }
}

// ---------------------------------------------------------------------------
// Flash attention (unchanged from round 3): two-pass, barrier-free,
// direct-global Q/K/V fragments, swapped QK^T, wave-local P LDS.
// ---------------------------------------------------------------------------
__global__ __launch_bounds__(256)
void attn_mfma(const u16* __restrict__ qt, const u16* __restrict__ kt,
               const u16* __restrict__ vv, const float* __restrict__ temp,
               u16* __restrict__ out) {
    __shared__ u16 lds[8192];
    const int tid = threadIdx.x, l = tid & 63, w = tid >> 6;
    const int g = l >> 4, c = l & 15;
    const int swz = (c & 7) ^ ((c & 8) >> 1);
    const int n0 = blockIdx.x * 128;
    const int h = blockIdx.y, b = blockIdx.z;
    const int bh = b * NHEAD + h;
    const float t2 = temp[h] * L2E;
    u16* P = lds + w * 2048;

    const u16* qb = qt + ((size_t)bh * HW + n0 + w * 32) * 32;
    const u16* kb = kt + (size_t)bh * HW * 32;
    const u16* vb = vv + ((size_t)b * CCH + h * 32) * HW;

    bf16x8 qf[2];
#pragma unroll
    for (int it = 0; it < 2; ++it)
        qf[it] = *(const bf16x8*)(qb + (it * 16 + c) * 32 + g * 8);

    float mx[2] = { -3.0e38f, -3.0e38f };
    for (int t = 0; t < 16; ++t) {
        const u16* kp = kb + (size_t)(t * 64) * 32;
        bf16x8 kf[4];
#pragma unroll
        for (int nj = 0; nj < 4; ++nj)
            kf[nj] = *(const bf16x8*)(kp + (nj * 16 + c) * 32 + g * 8);
#pragma unroll
        for (int it = 0; it < 2; ++it)
#pragma unroll
            for (int nj = 0; nj < 4; ++nj) {
                f32x4 s = __builtin_amdgcn_mfma_f32_16x16x32_bf16(
                    kf[nj], qf[it], (f32x4)0.f, 0, 0, 0);
#pragma unroll
                for (int r = 0; r < 4; ++r) mx[it] = fmaxf(mx[it], s[r] * t2);
            }
    }
#pragma unroll
    for (int it = 0; it < 2; ++it) {
        mx[it] = fmaxf(mx[it], __shfl_xor(mx[it], 16));
        mx[it] = fmaxf(mx[it], __shfl_xor(mx[it], 32));
    }

    float lac[2] = { 0.f, 0.f };
    f32x4 o[2][2];
    o[0][0] = (f32x4)0.f; o[0][1] = (f32x4)0.f;
    o[1][0] = (f32x4)0.f; o[1][1] = (f32x4)0.f;

    for (int t = 0; t < 16; ++t) {
        const int kv0 = t * 64;
        const u16* kp = kb + (size_t)kv0 * 32;
        bf16x8 kf[4];
#pragma unroll
        for (int nj = 0; nj < 4; ++nj)
            kf[nj] = *(const bf16x8*)(kp + (nj * 16 + c) * 32 + g * 8);
        f32x4 s[2][4];
#pragma unroll
        for (int it = 0; it < 2; ++it)
#pragma unroll
            for (int nj = 0; nj < 4; ++nj)
                s[it][nj] = __builtin_amdgcn_mfma_f32_16x16x32_bf16(
                    kf[nj], qf[it], (f32x4)0.f, 0, 0, 0);
        bf16x8 vf[2][2];
#pragma unroll
        for (int kj = 0; kj < 2; ++kj)
#pragma unroll
            for (int dv = 0; dv < 2; ++dv)
                vf[kj][dv] = *(const bf16x8*)(vb + (size_t)(dv * 16 + c) * HW
                                              + kv0 + kj * 32 + g * 8);
#pragma unroll
        for (int it = 0; it < 2; ++it) {
            const int row = it * 16 + c;
#pragma unroll
            for (int nj = 0; nj < 4; ++nj) {
                float p0 = exp2f(fmaf(s[it][nj][0], t2, -mx[it]));
                float p1 = exp2f(fmaf(s[it][nj][1], t2, -mx[it]));
                float p2 = exp2f(fmaf(s[it][nj][2], t2, -mx[it]));
                float p3 = exp2f(fmaf(s[it][nj][3], t2, -mx[it]));
                lac[it] += (p0 + p1) + (p2 + p3);
                uint2 pk;
                pk.x = cvt_pk_bf16(p0, p1);
                pk.y = cvt_pk_bf16(p2, p3);
                int ck = (2 * nj + (g >> 1)) ^ swz;
                *(uint2*)(&P[row * 64 + ck * 8 + (g & 1) * 4]) = pk;
            }
        }
        asm volatile("s_waitcnt lgkmcnt(0)" ::: "memory");
        __builtin_amdgcn_sched_barrier(0);
#pragma unroll
        for (int it = 0; it < 2; ++it) {
            const int row = it * 16 + c;
#pragma unroll
            for (int kj = 0; kj < 2; ++kj) {
                bf16x8 pf = *(const bf16x8*)(&P[row * 64 + ((kj * 4 + g) ^ swz) * 8]);
#pragma unroll
                for (int dv = 0; dv < 2; ++dv)
                    o[it][dv] = __builtin_amdgcn_mfma_f32_16x16x32_bf16(
                        pf, vf[kj][dv], o[it][dv], 0, 0, 0);
            }
        }
    }

#pragma unroll
    for (int it = 0; it < 2; ++it) {
        lac[it] += __shfl_xor(lac[it], 16);
        lac[it] += __shfl_xor(lac[it], 32);
    }
    float inv0 = 1.0f / lac[0], inv1 = 1.0f / lac[1];
    float invr[2][4];
#pragma unroll
    for (int r = 0; r < 4; ++r) {
        int src = (l & 48) | (g * 4 + r);
        invr[0][r] = __shfl(inv0, src);
        invr[1][r] = __shfl(inv1, src);
    }
    asm volatile("s_waitcnt lgkmcnt(0)" ::: "memory");
    __builtin_amdgcn_sched_barrier(0);
#pragma unroll
    for (int it = 0; it < 2; ++it)
#pragma unroll
        for (int dv = 0; dv < 2; ++dv) {
            uint2 pk;
            pk.x = cvt_pk_bf16(o[it][dv][0] * invr[it][0], o[it][dv][1] * invr[it][1]);
            pk.y = cvt_pk_bf16(o[it][dv][2] * invr[it][2], o[it][dv][3] * invr[it][3]);
            *(uint2*)(&P[(dv * 16 + c) * 36 + it * 16 + g * 4]) = pk;
        }
    asm volatile("s_waitcnt lgkmcnt(0)" ::: "memory");
    __builtin_amdgcn_sched_barrier(0);
    {
        int dvl = l & 31, seg = l >> 5;
#pragma unroll
        for (int hf = 0; hf < 2; ++hf) {
            us4 a0 = *(const us4*)(&P[dvl * 36 + seg * 16 + hf * 8]);
            us4 a1 = *(const us4*)(&P[dvl * 36 + seg * 16 + hf * 8 + 4]);
            us8 ov = { a0[0], a0[1], a0[2], a0[3], a1[0], a1[1], a1[2], a1[3] };
            *(us8*)(out + ((size_t)b * CCH + h * 32 + dvl) * HW
                    + n0 + w * 32 + seg * 16 + hf * 8) = ov;
        }
    }
}

// ---------------------------------------------------------------------------
__global__ __launch_bounds__(256)
void dwgelu_bf16(const u16* __restrict__ in, const float* __restrict__ dw,
                 u16* __restrict__ out) {
    int gid = blockIdx.x * 256 + threadIdx.x;
    int x4 = (gid & 7) * 4;
    int y  = (gid >> 3) & 31;
    int bc = gid >> 8;
    int ch = bc & 1023;
    const float* wp = dw + ch * 9;
    const u16* ip = in + ((size_t)bc << 10);
    float acc[4] = {0.f, 0.f, 0.f, 0.f};
#pragma unroll
    for (int dy = -1; dy <= 1; ++dy) {
        int yy = y + dy;
        if ((unsigned)yy >= 32u) continue;
        const u16* rp = ip + yy * 32;
        float row[6];
        us4 c4 = *(const us4*)(rp + x4);
        row[1] = b2f(c4[0]); row[2] = b2f(c4[1]);
        row[3] = b2f(c4[2]); row[4] = b2f(c4[3]);
        row[0] = (x4 > 0)  ? b2f(rp[x4 - 1]) : 0.f;
        row[5] = (x4 < 28) ? b2f(rp[x4 + 4]) : 0.f;
        float w0 = wp[(dy + 1) * 3], w1 = wp[(dy + 1) * 3 + 1], w2 = wp[(dy + 1) * 3 + 2];
#pragma unroll
        for (int i = 0; i < 4; ++i)
            acc[i] += w0 * row[i] + w1 * row[i + 1] + w2 * row[i + 2];
    }
    us4 o;
#pragma unroll
    for (int i = 0; i < 4; ++i) {
        float ge = 0.5f * acc[i] * (1.0f + erff(acc[i] * 0.70710678118f));
        o[i] = f2b(ge);
    }
    *(us4*)(out + (size_t)gid * 4) = o;
}

// ---------------------------------------------------------------------------
extern "C" void kernel_launch(void* const* d_in, const int* in_sizes, int n_in,
                              void* d_out, int out_size, void* d_ws, size_t ws_size,
                              hipStream_t stream) {
    const float* x1     = (const float*)d_in[0];
    const float* x2     = (const float*)d_in[1];
    const float* bn1_g  = (const float*)d_in[2];
    const float* bn1_b  = (const float*)d_in[3];
    const float* bn1_m  = (const float*)d_in[4];
    const float* bn1_v  = (const float*)d_in[5];
    const float* q_w    = (const float*)d_in[6];
    const float* k_w    = (const float*)d_in[7];
    const float* v_w    = (const float*)d_in[8];
    const float* temp   = (const float*)d_in[9];
    const float* proj_w = (const float*)d_in[10];
    const float* proj_b = (const float*)d_in[11];
    const float* bn2_g  = (const float*)d_in[12];
    const float* bn2_b  = (const float*)d_in[13];
    const float* bn2_m  = (const float*)d_in[14];
    const float* bn2_v  = (const float*)d_in[15];
    const float* fc1_w  = (const float*)d_in[16];
    const float* fc1_b  = (const float*)d_in[17];
    const float* dw_w   = (const float*)d_in[18];
    const float* fc2_w  = (const float*)d_in[19];
    const float* fc2_b  = (const float*)d_in[20];

    const size_t SZ = (size_t)BATCH * CCH * HW;   // 2,097,152 elems
    float* coef = (float*)d_ws;                    // 1024 f32
    u16*   bp   = (u16*)(coef + 1024);
    u16* qwb   = bp;
    u16* kwb   = bp + 65536;
    u16* vwb   = bp + 131072;
    u16* pjwb  = bp + 196608;
    u16* fc1wb = bp + 262144;
    u16* fc2wb = bp + 524288;
    u16* qtb   = bp + 786432;        // [bh][n][d] transposed
    u16* ktb   = qtb + SZ;
    u16* vbuf  = ktb + SZ;           // [b][c][n]
    u16* attnb = vbuf + SZ;
    u16* x1n   = attnb + SZ;
    u16* x2n   = x1n + SZ;
    u16* ext   = x2n + SZ;           // 2*SZ fresh (tail of h2)
    float* y1  = (float*)(ext + 2 * SZ);
    u16* y1n   = (u16*)(y1 + SZ);
    u16* h1    = qtb;                // overlays qt,kt,v,attn (dead by fc1)
    u16* h2    = x1n;                // overlays x1n,x2n + ext (dead by dwgelu)

    bn_coef_kernel<<<1, 256, 0, stream>>>(bn1_g, bn1_b, bn1_m, bn1_v,
                                          bn2_g, bn2_b, bn2_m, bn2_v, coef);
    cvt_all<<<768, 256, 0, stream>>>(q_w, k_w, v_w, proj_w, fc1_w, fc2_w, bp);
    xbn2_kernel<<<4096, 256, 0, stream>>>(x1, x2, coef, coef + 256, x1n, x2n);

    qkv_gemm<<<dim3(16, 12, BATCH), 256, 0, stream>>>(qwb, kwb, vwb, x1n, x2n,
                                                      qtb, ktb, vbuf);

    attn_mfma<<<dim3(8, NHEAD, BATCH), 256, 0, stream>>>(qtb, ktb, vbuf, temp, attnb);

    // y1 = x1 + proj(attn) (fp32); y1n = bn2(y1) (bf16)
    gemm_bf16<<<dim3(16, 4, BATCH), 256, 0, stream>>>(pjwb, attnb, proj_b, x1,
                                                      y1, y1n, coef + 512, coef + 768,
                                                      CCH, CCH);
    // h1 = fc1(y1n) + b (bf16)
    gemm_bf16<<<dim3(16, 16, BATCH), 256, 0, stream>>>(fc1wb, y1n, fc1_b, nullptr,
                                                       nullptr, h1, nullptr, nullptr,
                                                       CCH, HIDC);
    // h2 = gelu(dw(h1))
    dwgelu_bf16<<<(BATCH * HIDC * HW) / 1024, 256, 0, stream>>>(h1, dw_w, h2);

    // out = y1 + fc2(h2) + b (fp32)
    gemm_bf16<<<dim3(16, 4, BATCH), 256, 0, stream>>>(fc2wb, h2, fc2_b, y1,
                                                      (float*)d_out, nullptr,
                                                      nullptr, nullptr, HIDC, CCH);
}